// Round 3
// baseline (979.180 us; speedup 1.0000x reference)
//
#include <hip/hip_runtime.h>
#include <hip/hip_bf16.h>
#include <stdint.h>

#define NTOK 8192
#define CDIM 1024
#define DIN  2048
#define NEXP 8
#define NSLOT (NTOK * 2)

typedef __bf16 bf16x8 __attribute__((ext_vector_type(8)));
typedef float  f32x4  __attribute__((ext_vector_type(4)));

typedef __attribute__((address_space(1))) const unsigned char GBUF;
typedef __attribute__((address_space(3))) unsigned char LBUF;

__device__ __forceinline__ void gload_lds16(const void* g, void* l) {
    __builtin_amdgcn_global_load_lds((GBUF*)g, (LBUF*)l, 16, 0, 0);
}

__device__ __forceinline__ ushort f2bf(float f) {
    union { float f; unsigned u; } v; v.f = f;
    unsigned u = v.u;
    u += 0x7fffu + ((u >> 16) & 1u);   // RNE
    return (ushort)(u >> 16);
}
__device__ __forceinline__ float bf2f(ushort u) {
    union { float f; unsigned u; } v; v.u = ((unsigned)u) << 16; return v.f;
}
__device__ __forceinline__ float silu_f(float x) { return x / (1.f + __expf(-x)); }

// swizzled LDS fragment read: row-major [128][64] ushort tile, 16B chunk XOR'd by row&7
__device__ __forceinline__ bf16x8 lds_swz(const ushort* L, int row, int kof) {
    return *(const bf16x8*)&L[row * 64 + ((((kof >> 3) ^ row) & 7) << 3)];
}

// ---------------- fp32 -> bf16 bulk convert ----------------
__global__ void __launch_bounds__(256) k_cvt(const float* __restrict__ src,
                                             ushort* __restrict__ dst, int n4) {
    int i = blockIdx.x * 256 + threadIdx.x;
    int stride = gridDim.x * 256;
    for (; i < n4; i += stride) {
        float4 v = ((const float4*)src)[i];
        ushort4 o;
        o.x = f2bf(v.x); o.y = f2bf(v.y); o.z = f2bf(v.z); o.w = f2bf(v.w);
        ((ushort4*)dst)[i] = o;
    }
}

// ---------------- router: one wave per token ----------------
__global__ void __launch_bounds__(256) k_router(
    const float* __restrict__ x, const float* __restrict__ Wr,
    const float* __restrict__ br, int* __restrict__ counts,
    int* __restrict__ tok_e, float* __restrict__ tok_w) {
    int wave = blockIdx.x * 4 + (threadIdx.x >> 6);
    int lane = threadIdx.x & 63;
    const float4* row = (const float4*)(x + (size_t)wave * CDIM);
    float acc[NEXP];
#pragma unroll
    for (int e = 0; e < NEXP; ++e) acc[e] = 0.f;
#pragma unroll
    for (int j = 0; j < 4; ++j) {
        float4 v = row[j * 64 + lane];
#pragma unroll
        for (int e = 0; e < NEXP; ++e) {
            float4 w = ((const float4*)(Wr + e * CDIM))[j * 64 + lane];
            acc[e] += v.x * w.x + v.y * w.y + v.z * w.z + v.w * w.w;
        }
    }
#pragma unroll
    for (int off = 32; off > 0; off >>= 1)
#pragma unroll
        for (int e = 0; e < NEXP; ++e) acc[e] += __shfl_xor(acc[e], off, 64);
    if (lane == 0) {
        float l[NEXP];
#pragma unroll
        for (int e = 0; e < NEXP; ++e) l[e] = acc[e] + br[e];
        int i0 = 0; float l0 = l[0];
#pragma unroll
        for (int e = 1; e < NEXP; ++e) if (l[e] > l0) { l0 = l[e]; i0 = e; }
        int i1 = -1; float l1 = -1e30f;
#pragma unroll
        for (int e = 0; e < NEXP; ++e) if (e != i0 && l[e] > l1) { l1 = l[e]; i1 = e; }
        float s  = __expf(l1 - l0);   // renormalized top-2 softmax
        float w0 = 1.f / (1.f + s);
        float w1 = 1.f - w0;
        tok_e[wave * 2] = i0; tok_e[wave * 2 + 1] = i1;
        tok_w[wave * 2] = w0; tok_w[wave * 2 + 1] = w1;
        atomicAdd(&counts[i0], 1); atomicAdd(&counts[i1], 1);
    }
}

// ---------------- scan + aux loss ----------------
__global__ void k_scan(const int* __restrict__ counts, int* __restrict__ offsets,
                       float* __restrict__ out_aux) {
    if (threadIdx.x == 0 && blockIdx.x == 0) {
        int o = 0;
        for (int e = 0; e < NEXP; ++e) { offsets[e] = o; o += counts[e]; }
        offsets[NEXP] = o;
        float aux = 0.f;
        for (int e = 0; e < NEXP; ++e) {
            float ld = (float)counts[e] * (1.f / (float)NTOK);
            aux += ld * ld;
        }
        *out_aux = aux;
    }
}

// ---------------- scatter tokens into expert-grouped slots ----------------
__global__ void __launch_bounds__(256) k_scatter(
    const int* __restrict__ tok_e, const float* __restrict__ tok_w,
    const int* __restrict__ offsets, int* __restrict__ cursor,
    int* __restrict__ perm_token, int* __restrict__ tok_slot) {
    int t = blockIdx.x * 256 + threadIdx.x;
    if (t >= NTOK) return;
#pragma unroll
    for (int k = 0; k < 2; ++k) {
        int e = tok_e[t * 2 + k];
        int pos = atomicAdd(&cursor[e], 1);
        int s = offsets[e] + pos;
        perm_token[s] = t;
        tok_slot[t * 2 + k] = s;
    }
}

// ---------------- grouped GEMM1 (bf16, dbuf prefetch, swizzled LDS) ----------------
// tile: 128 slots x 64 y-cols (dual: xi rows n0.., z rows DIN+n0..); BK=64
__global__ void __launch_bounds__(256) k_gemm1(
    const ushort* __restrict__ xb, const ushort* __restrict__ Winb,
    const float* __restrict__ conv_w, const float* __restrict__ conv_b,
    const float* __restrict__ Dp, const int* __restrict__ counts,
    const int* __restrict__ offsets, const int* __restrict__ perm_token,
    ushort* __restrict__ y) {
    int h = blockIdx.x;
    int vb = (h & 7) * 256 + (h >> 3);   // bijective: 2048 = 8*256, expert == XCD
    int e  = vb >> 8;
    int r  = vb & 255;
    int nt = r >> 3;      // 32 n-tiles over DIN
    int sp = r & 7;       // SPLITM = 8
    int cnt = counts[e];
    if (cnt == 0) return;
    int base = offsets[e];
    int mtiles = (cnt + 127) >> 7;
    int n0 = nt * 64;

    __shared__ ushort aL[2][128 * 64];
    __shared__ ushort bL[2][128 * 64];
    __shared__ int    s_tok[128];

    int tid = threadIdx.x, lane = tid & 63, w = tid >> 6;
    int wrow = w >> 1, wcol = w & 1;
    const ushort* WinE = Winb + (size_t)e * (2 * DIN) * CDIM;
    int lrow = lane >> 3;                     // row within 8-row staging block
    int schunk = ((lane & 7) ^ lrow) << 3;    // pre-swizzled source chunk (elements)

    uint bsrc[4];
#pragma unroll
    for (int i = 0; i < 4; ++i) {
        int rrow = (w + 4 * i) * 8 + lrow;    // 0..127
        int grow = (rrow < 64) ? (n0 + rrow) : (DIN + n0 + rrow - 64);
        bsrc[i] = (uint)grow * CDIM + schunk;
    }

#define STAGE1(bi, kk0) do { \
        gload_lds16(xb   + asrc[0] + (kk0), &aL[bi][(w +  0) * 512]); \
        gload_lds16(WinE + bsrc[0] + (kk0), &bL[bi][(w +  0) * 512]); \
        gload_lds16(xb   + asrc[1] + (kk0), &aL[bi][(w +  4) * 512]); \
        gload_lds16(WinE + bsrc[1] + (kk0), &bL[bi][(w +  4) * 512]); \
        gload_lds16(xb   + asrc[2] + (kk0), &aL[bi][(w +  8) * 512]); \
        gload_lds16(WinE + bsrc[2] + (kk0), &bL[bi][(w +  8) * 512]); \
        gload_lds16(xb   + asrc[3] + (kk0), &aL[bi][(w + 12) * 512]); \
        gload_lds16(WinE + bsrc[3] + (kk0), &bL[bi][(w + 12) * 512]); \
    } while (0)

    for (int mt = sp; mt < mtiles; mt += 8) {
        int rem = cnt - mt * 128;
        if (tid < 128) s_tok[tid] = perm_token[base + mt * 128 + (tid < rem ? tid : 0)];
        __syncthreads();
        uint asrc[4];
#pragma unroll
        for (int i = 0; i < 4; ++i)
            asrc[i] = (uint)s_tok[(w + 4 * i) * 8 + lrow] * CDIM + schunk;

        f32x4 accXi[4][2], accZ[4][2];
#pragma unroll
        for (int m = 0; m < 4; ++m)
#pragma unroll
            for (int n = 0; n < 2; ++n) {
                accXi[m][n] = f32x4{0.f, 0.f, 0.f, 0.f};
                accZ[m][n]  = f32x4{0.f, 0.f, 0.f, 0.f};
            }

        STAGE1(0, 0);
        __syncthreads();
#pragma unroll 2
        for (int kt = 0; kt < 16; ++kt) {
            int cur = kt & 1;
            if (kt < 15) STAGE1(cur ^ 1, (kt + 1) * 64);
            const ushort* A = &aL[cur][0];
            const ushort* B = &bL[cur][0];
#pragma unroll
            for (int kk = 0; kk < 64; kk += 32) {
                int kof = kk + (lane >> 4) * 8;
                bf16x8 af[4], bxi[2], bz[2];
#pragma unroll
                for (int m = 0; m < 4; ++m)
                    af[m] = lds_swz(A, wrow * 64 + m * 16 + (lane & 15), kof);
#pragma unroll
                for (int n = 0; n < 2; ++n) {
                    int cl = wcol * 32 + n * 16 + (lane & 15);
                    bxi[n] = lds_swz(B, cl, kof);
                    bz[n]  = lds_swz(B, 64 + cl, kof);
                }
#pragma unroll
                for (int m = 0; m < 4; ++m)
#pragma unroll
                    for (int n = 0; n < 2; ++n) {
                        accXi[m][n] = __builtin_amdgcn_mfma_f32_16x16x32_bf16(af[m], bxi[n], accXi[m][n], 0, 0, 0);
                        accZ[m][n]  = __builtin_amdgcn_mfma_f32_16x16x32_bf16(af[m], bz[n],  accZ[m][n],  0, 0, 0);
                    }
            }
            __syncthreads();
        }
        // epilogue: gated activation -> y (bf16)
#pragma unroll
        for (int n = 0; n < 2; ++n) {
            int c = n0 + wcol * 32 + n * 16 + (lane & 15);
            float cwl = conv_w[((size_t)e * DIN + c) * 4 + 3];
            float cb  = conv_b[(size_t)e * DIN + c];
            float dp  = Dp[(size_t)e * DIN + c];
#pragma unroll
            for (int m = 0; m < 4; ++m)
#pragma unroll
                for (int q = 0; q < 4; ++q) {
                    int rl = wrow * 64 + m * 16 + (lane >> 4) * 4 + q;
                    if (rl < rem) {
                        int slot = base + mt * 128 + rl;
                        float xi = accXi[m][n][q], z = accZ[m][n][q];
                        float yv = silu_f(xi * cwl + cb) * dp * silu_f(z);
                        y[(size_t)slot * DIN + c] = f2bf(yv);
                    }
                }
        }
    }
#undef STAGE1
}

// ---------------- grouped GEMM2 (bf16, dbuf prefetch, swizzled LDS) ----------------
// tile: 128 slots x 128 out-cols; writes per-slot bf16 results (no atomics)
__global__ void __launch_bounds__(256) k_gemm2(
    const ushort* __restrict__ y, const ushort* __restrict__ Woutb,
    const int* __restrict__ counts, const int* __restrict__ offsets,
    ushort* __restrict__ so) {
    int h = blockIdx.x;
    int vb = (h & 7) * 128 + (h >> 3);   // bijective: 1024 = 8*128
    int e  = vb >> 7;
    int r  = vb & 127;
    int nt = r >> 4;      // 8 n-tiles over CDIM
    int sp = r & 15;      // SPLITM = 16
    int cnt = counts[e];
    if (cnt == 0) return;
    int base = offsets[e];
    int mtiles = (cnt + 127) >> 7;
    int c0 = nt * 128;

    __shared__ ushort aL[2][128 * 64];
    __shared__ ushort bL[2][128 * 64];

    int tid = threadIdx.x, lane = tid & 63, w = tid >> 6;
    int wrow = w >> 1, wcol = w & 1;
    const ushort* WoutE = Woutb + (size_t)e * CDIM * DIN;
    int lrow = lane >> 3;
    int schunk = ((lane & 7) ^ lrow) << 3;

    uint bsrc[4];
#pragma unroll
    for (int i = 0; i < 4; ++i) {
        int rrow = (w + 4 * i) * 8 + lrow;
        bsrc[i] = (uint)(c0 + rrow) * DIN + schunk;
    }

#define STAGE2(bi, kk0) do { \
        gload_lds16(y     + asrc[0] + (kk0), &aL[bi][(w +  0) * 512]); \
        gload_lds16(WoutE + bsrc[0] + (kk0), &bL[bi][(w +  0) * 512]); \
        gload_lds16(y     + asrc[1] + (kk0), &aL[bi][(w +  4) * 512]); \
        gload_lds16(WoutE + bsrc[1] + (kk0), &bL[bi][(w +  4) * 512]); \
        gload_lds16(y     + asrc[2] + (kk0), &aL[bi][(w +  8) * 512]); \
        gload_lds16(WoutE + bsrc[2] + (kk0), &bL[bi][(w +  8) * 512]); \
        gload_lds16(y     + asrc[3] + (kk0), &aL[bi][(w + 12) * 512]); \
        gload_lds16(WoutE + bsrc[3] + (kk0), &bL[bi][(w + 12) * 512]); \
    } while (0)

    for (int mt = sp; mt < mtiles; mt += 16) {
        int rem = cnt - mt * 128;
        uint asrc[4];
#pragma unroll
        for (int i = 0; i < 4; ++i) {
            int rr = (w + 4 * i) * 8 + lrow;
            int slot = base + mt * 128 + (rr < rem ? rr : 0);
            asrc[i] = (uint)slot * DIN + schunk;
        }
        f32x4 acc[4][4];
#pragma unroll
        for (int m = 0; m < 4; ++m)
#pragma unroll
            for (int n = 0; n < 4; ++n) acc[m][n] = f32x4{0.f, 0.f, 0.f, 0.f};

        STAGE2(0, 0);
        __syncthreads();
#pragma unroll 2
        for (int kt = 0; kt < 32; ++kt) {
            int cur = kt & 1;
            if (kt < 31) STAGE2(cur ^ 1, (kt + 1) * 64);
            const ushort* A = &aL[cur][0];
            const ushort* B = &bL[cur][0];
#pragma unroll
            for (int kk = 0; kk < 64; kk += 32) {
                int kof = kk + (lane >> 4) * 8;
                bf16x8 af[4], bfr[4];
#pragma unroll
                for (int m = 0; m < 4; ++m)
                    af[m] = lds_swz(A, wrow * 64 + m * 16 + (lane & 15), kof);
#pragma unroll
                for (int n = 0; n < 4; ++n)
                    bfr[n] = lds_swz(B, wcol * 64 + n * 16 + (lane & 15), kof);
#pragma unroll
                for (int m = 0; m < 4; ++m)
#pragma unroll
                    for (int n = 0; n < 4; ++n)
                        acc[m][n] = __builtin_amdgcn_mfma_f32_16x16x32_bf16(af[m], bfr[n], acc[m][n], 0, 0, 0);
            }
            __syncthreads();
        }
        // epilogue: per-slot bf16 store (combined later)
#pragma unroll
        for (int m = 0; m < 4; ++m)
#pragma unroll
            for (int q = 0; q < 4; ++q) {
                int rl = wrow * 64 + m * 16 + (lane >> 4) * 4 + q;
                if (rl < rem) {
                    int slot = base + mt * 128 + rl;
#pragma unroll
                    for (int n = 0; n < 4; ++n) {
                        int col = c0 + wcol * 64 + n * 16 + (lane & 15);
                        so[(size_t)slot * CDIM + col] = f2bf(acc[m][n][q]);
                    }
                }
            }
    }
#undef STAGE2
}

// ---------------- combine: out[t] = w0*so[s0] + w1*so[s1] ----------------
__global__ void __launch_bounds__(256) k_combine(
    const ushort* __restrict__ so, const int* __restrict__ tok_slot,
    const float* __restrict__ tok_w, float* __restrict__ out) {
    int i = blockIdx.x * 256 + threadIdx.x;   // NTOK*128 threads
    int t  = i >> 7;
    int c8 = (i & 127) << 3;
    int s0 = tok_slot[t * 2], s1 = tok_slot[t * 2 + 1];
    float w0 = tok_w[t * 2],  w1 = tok_w[t * 2 + 1];
    uint4 a = *(const uint4*)(so + (size_t)s0 * CDIM + c8);
    uint4 b = *(const uint4*)(so + (size_t)s1 * CDIM + c8);
    const ushort* au = (const ushort*)&a;
    const ushort* bu = (const ushort*)&b;
    float4 o0, o1;
    o0.x = w0 * bf2f(au[0]) + w1 * bf2f(bu[0]);
    o0.y = w0 * bf2f(au[1]) + w1 * bf2f(bu[1]);
    o0.z = w0 * bf2f(au[2]) + w1 * bf2f(bu[2]);
    o0.w = w0 * bf2f(au[3]) + w1 * bf2f(bu[3]);
    o1.x = w0 * bf2f(au[4]) + w1 * bf2f(bu[4]);
    o1.y = w0 * bf2f(au[5]) + w1 * bf2f(bu[5]);
    o1.z = w0 * bf2f(au[6]) + w1 * bf2f(bu[6]);
    o1.w = w0 * bf2f(au[7]) + w1 * bf2f(bu[7]);
    float4* dst = (float4*)(out + (size_t)t * CDIM + c8);
    dst[0] = o0; dst[1] = o1;
}

extern "C" void kernel_launch(void* const* d_in, const int* in_sizes, int n_in,
                              void* d_out, int out_size, void* d_ws, size_t ws_size,
                              hipStream_t stream) {
    const float* x      = (const float*)d_in[0];
    const float* Wr     = (const float*)d_in[1];
    const float* br     = (const float*)d_in[2];
    const float* Win    = (const float*)d_in[3];
    const float* conv_w = (const float*)d_in[4];
    const float* conv_b = (const float*)d_in[5];
    const float* Dp     = (const float*)d_in[6];
    const float* Wout   = (const float*)d_in[7];
    float* out = (float*)d_out;

    char* ws = (char*)d_ws;
    int*    counts     = (int*)(ws + 0);
    int*    offsets    = (int*)(ws + 64);
    int*    cursor     = (int*)(ws + 128);
    int*    tok_e      = (int*)(ws + 4096);
    float*  tok_w      = (float*)(ws + 4096 + 1 * 65536);
    int*    perm_token = (int*)(ws + 4096 + 2 * 65536);
    int*    tok_slot   = (int*)(ws + 4096 + 3 * 65536);
    const size_t MB = 1u << 20;
    ushort* y     = (ushort*)(ws + MB);                               // 64 MB
    ushort* xb    = (ushort*)(ws + MB + 67108864);                    // 16 MB
    ushort* winb  = (ushort*)(ws + MB + 67108864 + 16777216);         // 64 MB
    ushort* woutb = (ushort*)(ws + MB + 67108864 + 16777216 + 67108864); // 32 MB
    ushort* so    = winb;  // slot_out aliases winb (dead after gemm1; 33.5 MB <= 64 MB)

    hipMemsetAsync(ws, 0, 256, stream);

    k_cvt<<<1024, 256, 0, stream>>>(x,    xb,    NTOK * CDIM / 4);
    k_cvt<<<2048, 256, 0, stream>>>(Win,  winb,  NEXP * 2 * DIN * CDIM / 4);
    k_cvt<<<1024, 256, 0, stream>>>(Wout, woutb, NEXP * CDIM * DIN / 4);

    k_router<<<NTOK / 4, 256, 0, stream>>>(x, Wr, br, counts, tok_e, tok_w);
    k_scan<<<1, 64, 0, stream>>>(counts, offsets, out + (size_t)NTOK * CDIM);
    k_scatter<<<NTOK / 256, 256, 0, stream>>>(tok_e, tok_w, offsets, cursor, perm_token, tok_slot);

    k_gemm1<<<NEXP * 32 * 8, 256, 0, stream>>>(xb, winb, conv_w, conv_b, Dp,
                                               counts, offsets, perm_token, y);
    k_gemm2<<<NEXP * 8 * 16, 256, 0, stream>>>(y, woutb, counts, offsets, so);
    k_combine<<<NTOK * 128 / 256, 256, 0, stream>>>(so, tok_slot, tok_w, out);
}

// Round 4
// 747.692 us; speedup vs baseline: 1.3096x; 1.3096x over previous
//
#include <hip/hip_runtime.h>
#include <hip/hip_bf16.h>
#include <stdint.h>

#define NTOK 8192
#define CDIM 1024
#define DIN  2048
#define NEXP 8
#define NSLOT (NTOK * 2)

typedef __bf16 bf16x8 __attribute__((ext_vector_type(8)));
typedef float  f32x4  __attribute__((ext_vector_type(4)));

typedef __attribute__((address_space(1))) const unsigned char GBUF;
typedef __attribute__((address_space(3))) unsigned char LBUF;

__device__ __forceinline__ void gload_lds16(const void* g, void* l) {
    __builtin_amdgcn_global_load_lds((GBUF*)g, (LBUF*)l, 16, 0, 0);
}

__device__ __forceinline__ ushort f2bf(float f) {
    union { float f; unsigned u; } v; v.f = f;
    unsigned u = v.u;
    u += 0x7fffu + ((u >> 16) & 1u);   // RNE
    return (ushort)(u >> 16);
}
__device__ __forceinline__ float bf2f(ushort u) {
    union { float f; unsigned u; } v; v.u = ((unsigned)u) << 16; return v.f;
}
__device__ __forceinline__ float silu_f(float x) { return x / (1.f + __expf(-x)); }

// swizzled LDS fragment read: row-major [R][64] ushort tile, 16B chunk XOR'd by row&7
__device__ __forceinline__ bf16x8 lds_swz(const ushort* L, int row, int kof) {
    return *(const bf16x8*)&L[row * 64 + ((((kof >> 3) ^ row) & 7) << 3)];
}

// ---------------- fp32 -> bf16 bulk convert ----------------
__global__ void __launch_bounds__(256) k_cvt(const float* __restrict__ src,
                                             ushort* __restrict__ dst, int n4) {
    int i = blockIdx.x * 256 + threadIdx.x;
    int stride = gridDim.x * 256;
    for (; i < n4; i += stride) {
        float4 v = ((const float4*)src)[i];
        ushort4 o;
        o.x = f2bf(v.x); o.y = f2bf(v.y); o.z = f2bf(v.z); o.w = f2bf(v.w);
        ((ushort4*)dst)[i] = o;
    }
}

// ---------------- router: one wave per token; also emits x in bf16 ----------------
__global__ void __launch_bounds__(256) k_router(
    const float* __restrict__ x, const float* __restrict__ Wr,
    const float* __restrict__ br, int* __restrict__ counts,
    int* __restrict__ tok_e, float* __restrict__ tok_w,
    ushort* __restrict__ xb) {
    int wave = blockIdx.x * 4 + (threadIdx.x >> 6);
    int lane = threadIdx.x & 63;
    const float4* row = (const float4*)(x + (size_t)wave * CDIM);
    ushort4* xrow = (ushort4*)(xb + (size_t)wave * CDIM);
    float acc[NEXP];
#pragma unroll
    for (int e = 0; e < NEXP; ++e) acc[e] = 0.f;
#pragma unroll
    for (int j = 0; j < 4; ++j) {
        float4 v = row[j * 64 + lane];
        ushort4 o;
        o.x = f2bf(v.x); o.y = f2bf(v.y); o.z = f2bf(v.z); o.w = f2bf(v.w);
        xrow[j * 64 + lane] = o;
#pragma unroll
        for (int e = 0; e < NEXP; ++e) {
            float4 w = ((const float4*)(Wr + e * CDIM))[j * 64 + lane];
            acc[e] += v.x * w.x + v.y * w.y + v.z * w.z + v.w * w.w;
        }
    }
#pragma unroll
    for (int off = 32; off > 0; off >>= 1)
#pragma unroll
        for (int e = 0; e < NEXP; ++e) acc[e] += __shfl_xor(acc[e], off, 64);
    if (lane == 0) {
        float l[NEXP];
#pragma unroll
        for (int e = 0; e < NEXP; ++e) l[e] = acc[e] + br[e];
        int i0 = 0; float l0 = l[0];
#pragma unroll
        for (int e = 1; e < NEXP; ++e) if (l[e] > l0) { l0 = l[e]; i0 = e; }
        int i1 = -1; float l1 = -1e30f;
#pragma unroll
        for (int e = 0; e < NEXP; ++e) if (e != i0 && l[e] > l1) { l1 = l[e]; i1 = e; }
        float s  = __expf(l1 - l0);   // renormalized top-2 softmax
        float w0 = 1.f / (1.f + s);
        float w1 = 1.f - w0;
        tok_e[wave * 2] = i0; tok_e[wave * 2 + 1] = i1;
        tok_w[wave * 2] = w0; tok_w[wave * 2 + 1] = w1;
        atomicAdd(&counts[i0], 1); atomicAdd(&counts[i1], 1);
    }
}

// ---------------- scan + aux loss ----------------
__global__ void k_scan(const int* __restrict__ counts, int* __restrict__ offsets,
                       float* __restrict__ out_aux) {
    if (threadIdx.x == 0 && blockIdx.x == 0) {
        int o = 0;
        for (int e = 0; e < NEXP; ++e) { offsets[e] = o; o += counts[e]; }
        offsets[NEXP] = o;
        float aux = 0.f;
        for (int e = 0; e < NEXP; ++e) {
            float ld = (float)counts[e] * (1.f / (float)NTOK);
            aux += ld * ld;
        }
        *out_aux = aux;
    }
}

// ---------------- scatter tokens into expert-grouped slots ----------------
__global__ void __launch_bounds__(256) k_scatter(
    const int* __restrict__ tok_e, const float* __restrict__ tok_w,
    const int* __restrict__ offsets, int* __restrict__ cursor,
    int* __restrict__ perm_token, int* __restrict__ tok_slot) {
    int t = blockIdx.x * 256 + threadIdx.x;
    if (t >= NTOK) return;
#pragma unroll
    for (int k = 0; k < 2; ++k) {
        int e = tok_e[t * 2 + k];
        int pos = atomicAdd(&cursor[e], 1);
        int s = offsets[e] + pos;
        perm_token[s] = t;
        tok_slot[t * 2 + k] = s;
    }
}

// ---------------- grouped GEMM1 (bf16, single-buffer, swizzled LDS) ----------------
// tile: 128 slots x 64 y-cols (dual: xi rows n0.., z rows DIN+n0..); BK=64
__global__ void __launch_bounds__(256) k_gemm1(
    const ushort* __restrict__ xb, const ushort* __restrict__ Winb,
    const float* __restrict__ conv_w, const float* __restrict__ conv_b,
    const float* __restrict__ Dp, const int* __restrict__ counts,
    const int* __restrict__ offsets, const int* __restrict__ perm_token,
    ushort* __restrict__ y) {
    int h = blockIdx.x;
    int vb = (h & 7) * 256 + (h >> 3);   // bijective: 2048 = 8*256, expert == XCD
    int e  = vb >> 8;
    int r  = vb & 255;
    int nt = r >> 3;      // 32 n-tiles over DIN
    int sp = r & 7;       // SPLITM = 8
    int cnt = counts[e];
    if (cnt == 0) return;
    int base = offsets[e];
    int mtiles = (cnt + 127) >> 7;
    int n0 = nt * 64;

    __shared__ ushort aL[128 * 64];
    __shared__ ushort bL[128 * 64];
    __shared__ int    s_tok[128];

    int tid = threadIdx.x, lane = tid & 63, w = tid >> 6;
    int wrow = w >> 1, wcol = w & 1;
    const ushort* WinE = Winb + (size_t)e * (2 * DIN) * CDIM;
    int lrow = lane >> 3;                     // row within 8-row staging block
    int schunk = ((lane & 7) ^ lrow) << 3;    // pre-swizzled source chunk (elements)

    uint bsrc[4];
#pragma unroll
    for (int i = 0; i < 4; ++i) {
        int rrow = (w + 4 * i) * 8 + lrow;    // 0..127
        int grow = (rrow < 64) ? (n0 + rrow) : (DIN + n0 + rrow - 64);
        bsrc[i] = (uint)grow * CDIM + schunk;
    }

#define STAGE1(kk0) do { \
        gload_lds16(xb   + asrc[0] + (kk0), &aL[(w +  0) * 512]); \
        gload_lds16(WinE + bsrc[0] + (kk0), &bL[(w +  0) * 512]); \
        gload_lds16(xb   + asrc[1] + (kk0), &aL[(w +  4) * 512]); \
        gload_lds16(WinE + bsrc[1] + (kk0), &bL[(w +  4) * 512]); \
        gload_lds16(xb   + asrc[2] + (kk0), &aL[(w +  8) * 512]); \
        gload_lds16(WinE + bsrc[2] + (kk0), &bL[(w +  8) * 512]); \
        gload_lds16(xb   + asrc[3] + (kk0), &aL[(w + 12) * 512]); \
        gload_lds16(WinE + bsrc[3] + (kk0), &bL[(w + 12) * 512]); \
    } while (0)

    for (int mt = sp; mt < mtiles; mt += 8) {
        int rem = cnt - mt * 128;
        if (tid < 128) s_tok[tid] = perm_token[base + mt * 128 + (tid < rem ? tid : 0)];
        __syncthreads();
        uint asrc[4];
#pragma unroll
        for (int i = 0; i < 4; ++i)
            asrc[i] = (uint)s_tok[(w + 4 * i) * 8 + lrow] * CDIM + schunk;

        f32x4 accXi[4][2], accZ[4][2];
#pragma unroll
        for (int m = 0; m < 4; ++m)
#pragma unroll
            for (int n = 0; n < 2; ++n) {
                accXi[m][n] = f32x4{0.f, 0.f, 0.f, 0.f};
                accZ[m][n]  = f32x4{0.f, 0.f, 0.f, 0.f};
            }

        for (int kt = 0; kt < 16; ++kt) {
            STAGE1(kt * 64);
            __syncthreads();
#pragma unroll
            for (int kk = 0; kk < 64; kk += 32) {
                int kof = kk + (lane >> 4) * 8;
                bf16x8 af[4], bxi[2], bz[2];
#pragma unroll
                for (int m = 0; m < 4; ++m)
                    af[m] = lds_swz(aL, wrow * 64 + m * 16 + (lane & 15), kof);
#pragma unroll
                for (int n = 0; n < 2; ++n) {
                    int cl = wcol * 32 + n * 16 + (lane & 15);
                    bxi[n] = lds_swz(bL, cl, kof);
                    bz[n]  = lds_swz(bL, 64 + cl, kof);
                }
#pragma unroll
                for (int m = 0; m < 4; ++m)
#pragma unroll
                    for (int n = 0; n < 2; ++n) {
                        accXi[m][n] = __builtin_amdgcn_mfma_f32_16x16x32_bf16(af[m], bxi[n], accXi[m][n], 0, 0, 0);
                        accZ[m][n]  = __builtin_amdgcn_mfma_f32_16x16x32_bf16(af[m], bz[n],  accZ[m][n],  0, 0, 0);
                    }
            }
            __syncthreads();
        }
        // epilogue: gated activation -> y (bf16)
#pragma unroll
        for (int n = 0; n < 2; ++n) {
            int c = n0 + wcol * 32 + n * 16 + (lane & 15);
            float cwl = conv_w[((size_t)e * DIN + c) * 4 + 3];
            float cb  = conv_b[(size_t)e * DIN + c];
            float dp  = Dp[(size_t)e * DIN + c];
#pragma unroll
            for (int m = 0; m < 4; ++m)
#pragma unroll
                for (int q = 0; q < 4; ++q) {
                    int rl = wrow * 64 + m * 16 + (lane >> 4) * 4 + q;
                    if (rl < rem) {
                        int slot = base + mt * 128 + rl;
                        float xi = accXi[m][n][q], z = accZ[m][n][q];
                        float yv = silu_f(xi * cwl + cb) * dp * silu_f(z);
                        y[(size_t)slot * DIN + c] = f2bf(yv);
                    }
                }
        }
        __syncthreads();
    }
#undef STAGE1
}

// ---------------- grouped GEMM2 (bf16, single-buffer, swizzled LDS) ----------------
// tile: 128 slots x 128 out-cols; writes per-slot bf16 results (no atomics)
__global__ void __launch_bounds__(256) k_gemm2(
    const ushort* __restrict__ y, const ushort* __restrict__ Woutb,
    const int* __restrict__ counts, const int* __restrict__ offsets,
    ushort* __restrict__ so) {
    int h = blockIdx.x;
    int vb = (h & 7) * 128 + (h >> 3);   // bijective: 1024 = 8*128
    int e  = vb >> 7;
    int r  = vb & 127;
    int nt = r >> 4;      // 8 n-tiles over CDIM
    int sp = r & 15;      // SPLITM = 16
    int cnt = counts[e];
    if (cnt == 0) return;
    int base = offsets[e];
    int mtiles = (cnt + 127) >> 7;
    int c0 = nt * 128;

    __shared__ ushort aL[128 * 64];
    __shared__ ushort bL[128 * 64];

    int tid = threadIdx.x, lane = tid & 63, w = tid >> 6;
    int wrow = w >> 1, wcol = w & 1;
    const ushort* WoutE = Woutb + (size_t)e * CDIM * DIN;
    int lrow = lane >> 3;
    int schunk = ((lane & 7) ^ lrow) << 3;

    uint bsrc[4];
#pragma unroll
    for (int i = 0; i < 4; ++i) {
        int rrow = (w + 4 * i) * 8 + lrow;
        bsrc[i] = (uint)(c0 + rrow) * DIN + schunk;
    }

#define STAGE2(kk0) do { \
        gload_lds16(y     + asrc[0] + (kk0), &aL[(w +  0) * 512]); \
        gload_lds16(WoutE + bsrc[0] + (kk0), &bL[(w +  0) * 512]); \
        gload_lds16(y     + asrc[1] + (kk0), &aL[(w +  4) * 512]); \
        gload_lds16(WoutE + bsrc[1] + (kk0), &bL[(w +  4) * 512]); \
        gload_lds16(y     + asrc[2] + (kk0), &aL[(w +  8) * 512]); \
        gload_lds16(WoutE + bsrc[2] + (kk0), &bL[(w +  8) * 512]); \
        gload_lds16(y     + asrc[3] + (kk0), &aL[(w + 12) * 512]); \
        gload_lds16(WoutE + bsrc[3] + (kk0), &bL[(w + 12) * 512]); \
    } while (0)

    for (int mt = sp; mt < mtiles; mt += 16) {
        int rem = cnt - mt * 128;
        uint asrc[4];
#pragma unroll
        for (int i = 0; i < 4; ++i) {
            int rr = (w + 4 * i) * 8 + lrow;
            int slot = base + mt * 128 + (rr < rem ? rr : 0);
            asrc[i] = (uint)slot * DIN + schunk;
        }
        f32x4 acc[4][4];
#pragma unroll
        for (int m = 0; m < 4; ++m)
#pragma unroll
            for (int n = 0; n < 4; ++n) acc[m][n] = f32x4{0.f, 0.f, 0.f, 0.f};

        for (int kt = 0; kt < 32; ++kt) {
            STAGE2(kt * 64);
            __syncthreads();
#pragma unroll
            for (int kk = 0; kk < 64; kk += 32) {
                int kof = kk + (lane >> 4) * 8;
                bf16x8 af[4], bfr[4];
#pragma unroll
                for (int m = 0; m < 4; ++m)
                    af[m] = lds_swz(aL, wrow * 64 + m * 16 + (lane & 15), kof);
#pragma unroll
                for (int n = 0; n < 4; ++n)
                    bfr[n] = lds_swz(bL, wcol * 64 + n * 16 + (lane & 15), kof);
#pragma unroll
                for (int m = 0; m < 4; ++m)
#pragma unroll
                    for (int n = 0; n < 4; ++n)
                        acc[m][n] = __builtin_amdgcn_mfma_f32_16x16x32_bf16(af[m], bfr[n], acc[m][n], 0, 0, 0);
            }
            __syncthreads();
        }
        // epilogue: per-slot bf16 store (combined later)
#pragma unroll
        for (int m = 0; m < 4; ++m)
#pragma unroll
            for (int q = 0; q < 4; ++q) {
                int rl = wrow * 64 + m * 16 + (lane >> 4) * 4 + q;
                if (rl < rem) {
                    int slot = base + mt * 128 + rl;
#pragma unroll
                    for (int n = 0; n < 4; ++n) {
                        int col = c0 + wcol * 64 + n * 16 + (lane & 15);
                        so[(size_t)slot * CDIM + col] = f2bf(acc[m][n][q]);
                    }
                }
            }
    }
#undef STAGE2
}

// ---------------- combine: out[t] = w0*so[s0] + w1*so[s1] ----------------
__global__ void __launch_bounds__(256) k_combine(
    const ushort* __restrict__ so, const int* __restrict__ tok_slot,
    const float* __restrict__ tok_w, float* __restrict__ out) {
    int i = blockIdx.x * 256 + threadIdx.x;   // NTOK*128 threads
    int t  = i >> 7;
    int c8 = (i & 127) << 3;
    int s0 = tok_slot[t * 2], s1 = tok_slot[t * 2 + 1];
    float w0 = tok_w[t * 2],  w1 = tok_w[t * 2 + 1];
    uint4 a = *(const uint4*)(so + (size_t)s0 * CDIM + c8);
    uint4 b = *(const uint4*)(so + (size_t)s1 * CDIM + c8);
    const ushort* au = (const ushort*)&a;
    const ushort* bu = (const ushort*)&b;
    float4 o0, o1;
    o0.x = w0 * bf2f(au[0]) + w1 * bf2f(bu[0]);
    o0.y = w0 * bf2f(au[1]) + w1 * bf2f(bu[1]);
    o0.z = w0 * bf2f(au[2]) + w1 * bf2f(bu[2]);
    o0.w = w0 * bf2f(au[3]) + w1 * bf2f(bu[3]);
    o1.x = w0 * bf2f(au[4]) + w1 * bf2f(bu[4]);
    o1.y = w0 * bf2f(au[5]) + w1 * bf2f(bu[5]);
    o1.z = w0 * bf2f(au[6]) + w1 * bf2f(bu[6]);
    o1.w = w0 * bf2f(au[7]) + w1 * bf2f(bu[7]);
    float4* dst = (float4*)(out + (size_t)t * CDIM + c8);
    dst[0] = o0; dst[1] = o1;
}

extern "C" void kernel_launch(void* const* d_in, const int* in_sizes, int n_in,
                              void* d_out, int out_size, void* d_ws, size_t ws_size,
                              hipStream_t stream) {
    const float* x      = (const float*)d_in[0];
    const float* Wr     = (const float*)d_in[1];
    const float* br     = (const float*)d_in[2];
    const float* Win    = (const float*)d_in[3];
    const float* conv_w = (const float*)d_in[4];
    const float* conv_b = (const float*)d_in[5];
    const float* Dp     = (const float*)d_in[6];
    const float* Wout   = (const float*)d_in[7];
    float* out = (float*)d_out;

    char* ws = (char*)d_ws;
    int*    counts     = (int*)(ws + 0);
    int*    offsets    = (int*)(ws + 64);
    int*    cursor     = (int*)(ws + 128);
    int*    tok_e      = (int*)(ws + 4096);
    float*  tok_w      = (float*)(ws + 4096 + 1 * 65536);
    int*    perm_token = (int*)(ws + 4096 + 2 * 65536);
    int*    tok_slot   = (int*)(ws + 4096 + 3 * 65536);
    const size_t MB = 1u << 20;
    ushort* y     = (ushort*)(ws + MB);                               // 64 MB
    ushort* xb    = (ushort*)(ws + MB + 67108864);                    // 16 MB
    ushort* winb  = (ushort*)(ws + MB + 67108864 + 16777216);         // 64 MB
    ushort* woutb = (ushort*)(ws + MB + 67108864 + 16777216 + 67108864); // 32 MB
    ushort* so    = winb;  // slot_out aliases winb (dead after gemm1; 33.5 MB <= 64 MB)

    hipMemsetAsync(ws, 0, 256, stream);

    k_cvt<<<2048, 256, 0, stream>>>(Win,  winb,  NEXP * 2 * DIN * CDIM / 4);
    k_cvt<<<1024, 256, 0, stream>>>(Wout, woutb, NEXP * CDIM * DIN / 4);

    k_router<<<NTOK / 4, 256, 0, stream>>>(x, Wr, br, counts, tok_e, tok_w, xb);
    k_scan<<<1, 64, 0, stream>>>(counts, offsets, out + (size_t)NTOK * CDIM);
    k_scatter<<<NTOK / 256, 256, 0, stream>>>(tok_e, tok_w, offsets, cursor, perm_token, tok_slot);

    k_gemm1<<<NEXP * 32 * 8, 256, 0, stream>>>(xb, winb, conv_w, conv_b, Dp,
                                               counts, offsets, perm_token, y);
    k_gemm2<<<NEXP * 8 * 16, 256, 0, stream>>>(y, woutb, counts, offsets, so);
    k_combine<<<NTOK * 128 / 256, 256, 0, stream>>>(so, tok_slot, tok_w, out);
}

// Round 5
// 631.312 us; speedup vs baseline: 1.5510x; 1.1843x over previous
//
#include <hip/hip_runtime.h>
#include <hip/hip_bf16.h>
#include <stdint.h>

#define NTOK 8192
#define CDIM 1024
#define DIN  2048
#define NEXP 8
#define NSLOT (NTOK * 2)

typedef __bf16 bf16x8 __attribute__((ext_vector_type(8)));
typedef float  f32x4  __attribute__((ext_vector_type(4)));

typedef __attribute__((address_space(1))) const unsigned char GBUF;
typedef __attribute__((address_space(3))) unsigned char LBUF;

__device__ __forceinline__ void gload_lds16(const void* g, void* l) {
    __builtin_amdgcn_global_load_lds((GBUF*)g, (LBUF*)l, 16, 0, 0);
}

__device__ __forceinline__ ushort f2bf(float f) {
    union { float f; unsigned u; } v; v.f = f;
    unsigned u = v.u;
    u += 0x7fffu + ((u >> 16) & 1u);   // RNE
    return (ushort)(u >> 16);
}
__device__ __forceinline__ float bf2f(ushort u) {
    union { float f; unsigned u; } v; v.u = ((unsigned)u) << 16; return v.f;
}
__device__ __forceinline__ float silu_f(float x) { return x / (1.f + __expf(-x)); }

// swizzled LDS fragment read: row-major [R][64] ushort tile, 16B chunk XOR'd by row&7
__device__ __forceinline__ bf16x8 lds_swz(const ushort* L, int row, int kof) {
    return *(const bf16x8*)&L[row * 64 + ((((kof >> 3) ^ row) & 7) << 3)];
}

// ---------------- fp32 -> bf16 bulk convert ----------------
__global__ void __launch_bounds__(256) k_cvt(const float* __restrict__ src,
                                             ushort* __restrict__ dst, int n4) {
    int i = blockIdx.x * 256 + threadIdx.x;
    int stride = gridDim.x * 256;
    for (; i < n4; i += stride) {
        float4 v = ((const float4*)src)[i];
        ushort4 o;
        o.x = f2bf(v.x); o.y = f2bf(v.y); o.z = f2bf(v.z); o.w = f2bf(v.w);
        ((ushort4*)dst)[i] = o;
    }
}

// ---------------- router: one wave per token; also emits x in bf16 ----------------
__global__ void __launch_bounds__(256) k_router(
    const float* __restrict__ x, const float* __restrict__ Wr,
    const float* __restrict__ br, int* __restrict__ counts,
    int* __restrict__ tok_e, float* __restrict__ tok_w,
    ushort* __restrict__ xb) {
    int wave = blockIdx.x * 4 + (threadIdx.x >> 6);
    int lane = threadIdx.x & 63;
    const float4* row = (const float4*)(x + (size_t)wave * CDIM);
    ushort4* xrow = (ushort4*)(xb + (size_t)wave * CDIM);
    float acc[NEXP];
#pragma unroll
    for (int e = 0; e < NEXP; ++e) acc[e] = 0.f;
#pragma unroll
    for (int j = 0; j < 4; ++j) {
        float4 v = row[j * 64 + lane];
        ushort4 o;
        o.x = f2bf(v.x); o.y = f2bf(v.y); o.z = f2bf(v.z); o.w = f2bf(v.w);
        xrow[j * 64 + lane] = o;
#pragma unroll
        for (int e = 0; e < NEXP; ++e) {
            float4 w = ((const float4*)(Wr + e * CDIM))[j * 64 + lane];
            acc[e] += v.x * w.x + v.y * w.y + v.z * w.z + v.w * w.w;
        }
    }
#pragma unroll
    for (int off = 32; off > 0; off >>= 1)
#pragma unroll
        for (int e = 0; e < NEXP; ++e) acc[e] += __shfl_xor(acc[e], off, 64);
    if (lane == 0) {
        float l[NEXP];
#pragma unroll
        for (int e = 0; e < NEXP; ++e) l[e] = acc[e] + br[e];
        int i0 = 0; float l0 = l[0];
#pragma unroll
        for (int e = 1; e < NEXP; ++e) if (l[e] > l0) { l0 = l[e]; i0 = e; }
        int i1 = -1; float l1 = -1e30f;
#pragma unroll
        for (int e = 0; e < NEXP; ++e) if (e != i0 && l[e] > l1) { l1 = l[e]; i1 = e; }
        float s  = __expf(l1 - l0);   // renormalized top-2 softmax
        float w0 = 1.f / (1.f + s);
        float w1 = 1.f - w0;
        tok_e[wave * 2] = i0; tok_e[wave * 2 + 1] = i1;
        tok_w[wave * 2] = w0; tok_w[wave * 2 + 1] = w1;
        atomicAdd(&counts[i0], 1); atomicAdd(&counts[i1], 1);
    }
}

// ---------------- scan + aux loss ----------------
__global__ void k_scan(const int* __restrict__ counts, int* __restrict__ offsets,
                       float* __restrict__ out_aux) {
    if (threadIdx.x == 0 && blockIdx.x == 0) {
        int o = 0;
        for (int e = 0; e < NEXP; ++e) { offsets[e] = o; o += counts[e]; }
        offsets[NEXP] = o;
        float aux = 0.f;
        for (int e = 0; e < NEXP; ++e) {
            float ld = (float)counts[e] * (1.f / (float)NTOK);
            aux += ld * ld;
        }
        *out_aux = aux;
    }
}

// ---------------- scatter tokens into expert-grouped slots ----------------
__global__ void __launch_bounds__(256) k_scatter(
    const int* __restrict__ tok_e, const float* __restrict__ tok_w,
    const int* __restrict__ offsets, int* __restrict__ cursor,
    int* __restrict__ perm_token, int* __restrict__ tok_slot) {
    int t = blockIdx.x * 256 + threadIdx.x;
    if (t >= NTOK) return;
#pragma unroll
    for (int k = 0; k < 2; ++k) {
        int e = tok_e[t * 2 + k];
        int pos = atomicAdd(&cursor[e], 1);
        int s = offsets[e] + pos;
        perm_token[s] = t;
        tok_slot[t * 2 + k] = s;
    }
}

// ---------------- grouped GEMM1: 256 slots x 128 y-cols (dual), BK=64 ----------------
// 512 threads / 8 waves (4M x 2N), dbuf 128 KB LDS, issue-early/drain-late
__global__ void __launch_bounds__(512, 2) k_gemm1(
    const ushort* __restrict__ xb, const ushort* __restrict__ Winb,
    const float* __restrict__ conv_w, const float* __restrict__ conv_b,
    const float* __restrict__ Dp, const int* __restrict__ counts,
    const int* __restrict__ offsets, const int* __restrict__ perm_token,
    ushort* __restrict__ y) {
    int h = blockIdx.x;                  // 1280 = 8 * 160
    int vb = (h & 7) * 160 + (h >> 3);   // expert-per-XCD swizzle, bijective
    int e   = vb / 160;
    int r   = vb % 160;
    int mt0 = r >> 4;                    // 0..9
    int nt  = r & 15;                    // 0..15 over DIN/128
    int cnt = counts[e];
    if (cnt == 0) return;
    int base = offsets[e];
    int mtiles = (cnt + 255) >> 8;
    int n0 = nt * 128;

    __shared__ ushort aL[2][256 * 64];   // 2 x 32 KB
    __shared__ ushort bL[2][256 * 64];   // 2 x 32 KB (128 xi rows + 128 z rows)

    int tid = threadIdx.x, lane = tid & 63, w = tid >> 6;
    int Mw = w >> 1, Nw = w & 1;         // wave slice: 64 rows x 64 y-cols (dual)
    const ushort* WinE = Winb + (size_t)e * (2 * DIN) * CDIM;
    int schunk = ((tid & 7) ^ ((tid >> 3) & 7)) << 3;   // pre-swizzled source chunk

    uint bsrc[4];
#pragma unroll
    for (int i = 0; i < 4; ++i) {
        int rr = i * 64 + (tid >> 3);    // 0..255
        int grow = (rr < 128) ? (n0 + rr) : (DIN + n0 + (rr - 128));
        bsrc[i] = (uint)grow * CDIM + schunk;
    }

#define STAGE1(bi, kk0) do { \
        gload_lds16(xb   + asrc[0] + (kk0), &aL[bi][(0 * 512 + tid) * 8]); \
        gload_lds16(xb   + asrc[1] + (kk0), &aL[bi][(1 * 512 + tid) * 8]); \
        gload_lds16(xb   + asrc[2] + (kk0), &aL[bi][(2 * 512 + tid) * 8]); \
        gload_lds16(xb   + asrc[3] + (kk0), &aL[bi][(3 * 512 + tid) * 8]); \
        gload_lds16(WinE + bsrc[0] + (kk0), &bL[bi][(0 * 512 + tid) * 8]); \
        gload_lds16(WinE + bsrc[1] + (kk0), &bL[bi][(1 * 512 + tid) * 8]); \
        gload_lds16(WinE + bsrc[2] + (kk0), &bL[bi][(2 * 512 + tid) * 8]); \
        gload_lds16(WinE + bsrc[3] + (kk0), &bL[bi][(3 * 512 + tid) * 8]); \
    } while (0)

    for (int mt = mt0; mt < mtiles; mt += 10) {
        int rem = cnt - mt * 256;
        uint asrc[4];
#pragma unroll
        for (int i = 0; i < 4; ++i) {
            int rr = i * 64 + (tid >> 3);
            int sidx = base + mt * 256 + (rr < rem ? rr : 0);
            asrc[i] = (uint)perm_token[sidx] * CDIM + schunk;
        }

        f32x4 accXi[4][4], accZ[4][4];
#pragma unroll
        for (int m = 0; m < 4; ++m)
#pragma unroll
            for (int n = 0; n < 4; ++n) {
                accXi[m][n] = f32x4{0.f, 0.f, 0.f, 0.f};
                accZ[m][n]  = f32x4{0.f, 0.f, 0.f, 0.f};
            }

        STAGE1(0, 0);
        __syncthreads();
#pragma unroll 2
        for (int kt = 0; kt < 16; ++kt) {
            int cur = kt & 1;
            if (kt < 15) STAGE1(cur ^ 1, (kt + 1) * 64);   // issue-early
            const ushort* A = &aL[cur][0];
            const ushort* B = &bL[cur][0];
#pragma unroll
            for (int kk = 0; kk < 64; kk += 32) {
                int kof = kk + (lane >> 4) * 8;
                bf16x8 af[4], bxi[4], bz[4];
#pragma unroll
                for (int m = 0; m < 4; ++m)
                    af[m] = lds_swz(A, Mw * 64 + m * 16 + (lane & 15), kof);
#pragma unroll
                for (int n = 0; n < 4; ++n) {
                    int cl = Nw * 64 + n * 16 + (lane & 15);
                    bxi[n] = lds_swz(B, cl, kof);
                    bz[n]  = lds_swz(B, 128 + cl, kof);
                }
#pragma unroll
                for (int m = 0; m < 4; ++m)
#pragma unroll
                    for (int n = 0; n < 4; ++n) {
                        accXi[m][n] = __builtin_amdgcn_mfma_f32_16x16x32_bf16(af[m], bxi[n], accXi[m][n], 0, 0, 0);
                        accZ[m][n]  = __builtin_amdgcn_mfma_f32_16x16x32_bf16(af[m], bz[n],  accZ[m][n],  0, 0, 0);
                    }
            }
            __syncthreads();   // drain-late: vmcnt(0)+barrier, next buf ready
        }
        // epilogue: gated activation -> y (bf16)
#pragma unroll
        for (int n = 0; n < 4; ++n) {
            int c = n0 + Nw * 64 + n * 16 + (lane & 15);
            float cwl = conv_w[((size_t)e * DIN + c) * 4 + 3];
            float cb  = conv_b[(size_t)e * DIN + c];
            float dp  = Dp[(size_t)e * DIN + c];
#pragma unroll
            for (int m = 0; m < 4; ++m)
#pragma unroll
                for (int q = 0; q < 4; ++q) {
                    int rl = Mw * 64 + m * 16 + (lane >> 4) * 4 + q;
                    if (rl < rem) {
                        int slot = base + mt * 256 + rl;
                        float xi = accXi[m][n][q], z = accZ[m][n][q];
                        float yv = silu_f(xi * cwl + cb) * dp * silu_f(z);
                        y[(size_t)slot * DIN + c] = f2bf(yv);
                    }
                }
        }
    }
#undef STAGE1
}

// ---------------- grouped GEMM2: 256 slots x 128 out-cols, BK=64 ----------------
// 512 threads / 8 waves (4M x 2N), dbuf 96 KB LDS, issue-early/drain-late
__global__ void __launch_bounds__(512, 2) k_gemm2(
    const ushort* __restrict__ y, const ushort* __restrict__ Woutb,
    const int* __restrict__ counts, const int* __restrict__ offsets,
    ushort* __restrict__ so) {
    int h = blockIdx.x;                  // 640 = 8 * 80
    int vb = (h & 7) * 80 + (h >> 3);    // bijective
    int e   = vb / 80;
    int r   = vb % 80;
    int mt0 = r >> 3;                    // 0..9
    int nt  = r & 7;                     // 0..7 over CDIM/128
    int cnt = counts[e];
    if (cnt == 0) return;
    int base = offsets[e];
    int mtiles = (cnt + 255) >> 8;
    int c0 = nt * 128;

    __shared__ ushort aL[2][256 * 64];   // 2 x 32 KB
    __shared__ ushort bL[2][128 * 64];   // 2 x 16 KB

    int tid = threadIdx.x, lane = tid & 63, w = tid >> 6;
    int Mw = w >> 1, Nw = w & 1;
    const ushort* WoutE = Woutb + (size_t)e * CDIM * DIN;
    int schunk = ((tid & 7) ^ ((tid >> 3) & 7)) << 3;

    uint bsrc[2];
#pragma unroll
    for (int i = 0; i < 2; ++i) {
        int rr = i * 64 + (tid >> 3);    // 0..127
        bsrc[i] = (uint)(c0 + rr) * DIN + schunk;
    }

#define STAGE2(bi, kk0) do { \
        gload_lds16(y     + asrc[0] + (kk0), &aL[bi][(0 * 512 + tid) * 8]); \
        gload_lds16(y     + asrc[1] + (kk0), &aL[bi][(1 * 512 + tid) * 8]); \
        gload_lds16(y     + asrc[2] + (kk0), &aL[bi][(2 * 512 + tid) * 8]); \
        gload_lds16(y     + asrc[3] + (kk0), &aL[bi][(3 * 512 + tid) * 8]); \
        gload_lds16(WoutE + bsrc[0] + (kk0), &bL[bi][(0 * 512 + tid) * 8]); \
        gload_lds16(WoutE + bsrc[1] + (kk0), &bL[bi][(1 * 512 + tid) * 8]); \
    } while (0)

    for (int mt = mt0; mt < mtiles; mt += 10) {
        int rem = cnt - mt * 256;
        uint asrc[4];
#pragma unroll
        for (int i = 0; i < 4; ++i) {
            int rr = i * 64 + (tid >> 3);
            int slot = base + mt * 256 + (rr < rem ? rr : 0);
            asrc[i] = (uint)slot * DIN + schunk;
        }
        f32x4 acc[4][4];
#pragma unroll
        for (int m = 0; m < 4; ++m)
#pragma unroll
            for (int n = 0; n < 4; ++n) acc[m][n] = f32x4{0.f, 0.f, 0.f, 0.f};

        STAGE2(0, 0);
        __syncthreads();
#pragma unroll 2
        for (int kt = 0; kt < 32; ++kt) {
            int cur = kt & 1;
            if (kt < 31) STAGE2(cur ^ 1, (kt + 1) * 64);
            const ushort* A = &aL[cur][0];
            const ushort* B = &bL[cur][0];
#pragma unroll
            for (int kk = 0; kk < 64; kk += 32) {
                int kof = kk + (lane >> 4) * 8;
                bf16x8 af[4], bfr[4];
#pragma unroll
                for (int m = 0; m < 4; ++m)
                    af[m] = lds_swz(A, Mw * 64 + m * 16 + (lane & 15), kof);
#pragma unroll
                for (int n = 0; n < 4; ++n)
                    bfr[n] = lds_swz(B, Nw * 64 + n * 16 + (lane & 15), kof);
#pragma unroll
                for (int m = 0; m < 4; ++m)
#pragma unroll
                    for (int n = 0; n < 4; ++n)
                        acc[m][n] = __builtin_amdgcn_mfma_f32_16x16x32_bf16(af[m], bfr[n], acc[m][n], 0, 0, 0);
            }
            __syncthreads();
        }
        // epilogue: per-slot bf16 store (combined later)
#pragma unroll
        for (int m = 0; m < 4; ++m)
#pragma unroll
            for (int q = 0; q < 4; ++q) {
                int rl = Mw * 64 + m * 16 + (lane >> 4) * 4 + q;
                if (rl < rem) {
                    int slot = base + mt * 256 + rl;
#pragma unroll
                    for (int n = 0; n < 4; ++n) {
                        int col = c0 + Nw * 64 + n * 16 + (lane & 15);
                        so[(size_t)slot * CDIM + col] = f2bf(acc[m][n][q]);
                    }
                }
            }
    }
#undef STAGE2
}

// ---------------- combine: out[t] = w0*so[s0] + w1*so[s1] ----------------
__global__ void __launch_bounds__(256) k_combine(
    const ushort* __restrict__ so, const int* __restrict__ tok_slot,
    const float* __restrict__ tok_w, float* __restrict__ out) {
    int i = blockIdx.x * 256 + threadIdx.x;   // NTOK*128 threads
    int t  = i >> 7;
    int c8 = (i & 127) << 3;
    int s0 = tok_slot[t * 2], s1 = tok_slot[t * 2 + 1];
    float w0 = tok_w[t * 2],  w1 = tok_w[t * 2 + 1];
    uint4 a = *(const uint4*)(so + (size_t)s0 * CDIM + c8);
    uint4 b = *(const uint4*)(so + (size_t)s1 * CDIM + c8);
    const ushort* au = (const ushort*)&a;
    const ushort* bu = (const ushort*)&b;
    float4 o0, o1;
    o0.x = w0 * bf2f(au[0]) + w1 * bf2f(bu[0]);
    o0.y = w0 * bf2f(au[1]) + w1 * bf2f(bu[1]);
    o0.z = w0 * bf2f(au[2]) + w1 * bf2f(bu[2]);
    o0.w = w0 * bf2f(au[3]) + w1 * bf2f(bu[3]);
    o1.x = w0 * bf2f(au[4]) + w1 * bf2f(bu[4]);
    o1.y = w0 * bf2f(au[5]) + w1 * bf2f(bu[5]);
    o1.z = w0 * bf2f(au[6]) + w1 * bf2f(bu[6]);
    o1.w = w0 * bf2f(au[7]) + w1 * bf2f(bu[7]);
    float4* dst = (float4*)(out + (size_t)t * CDIM + c8);
    dst[0] = o0; dst[1] = o1;
}

extern "C" void kernel_launch(void* const* d_in, const int* in_sizes, int n_in,
                              void* d_out, int out_size, void* d_ws, size_t ws_size,
                              hipStream_t stream) {
    const float* x      = (const float*)d_in[0];
    const float* Wr     = (const float*)d_in[1];
    const float* br     = (const float*)d_in[2];
    const float* Win    = (const float*)d_in[3];
    const float* conv_w = (const float*)d_in[4];
    const float* conv_b = (const float*)d_in[5];
    const float* Dp     = (const float*)d_in[6];
    const float* Wout   = (const float*)d_in[7];
    float* out = (float*)d_out;

    char* ws = (char*)d_ws;
    int*    counts     = (int*)(ws + 0);
    int*    offsets    = (int*)(ws + 64);
    int*    cursor     = (int*)(ws + 128);
    int*    tok_e      = (int*)(ws + 4096);
    float*  tok_w      = (float*)(ws + 4096 + 1 * 65536);
    int*    perm_token = (int*)(ws + 4096 + 2 * 65536);
    int*    tok_slot   = (int*)(ws + 4096 + 3 * 65536);
    const size_t MB = 1u << 20;
    ushort* y     = (ushort*)(ws + MB);                               // 64 MB
    ushort* xb    = (ushort*)(ws + MB + 67108864);                    // 16 MB
    ushort* winb  = (ushort*)(ws + MB + 67108864 + 16777216);         // 64 MB
    ushort* woutb = (ushort*)(ws + MB + 67108864 + 16777216 + 67108864); // 32 MB
    ushort* so    = winb;  // slot_out aliases winb (dead after gemm1; 33.5 MB <= 64 MB)

    hipMemsetAsync(ws, 0, 256, stream);

    k_cvt<<<2048, 256, 0, stream>>>(Win,  winb,  NEXP * 2 * DIN * CDIM / 4);
    k_cvt<<<1024, 256, 0, stream>>>(Wout, woutb, NEXP * CDIM * DIN / 4);

    k_router<<<NTOK / 4, 256, 0, stream>>>(x, Wr, br, counts, tok_e, tok_w, xb);
    k_scan<<<1, 64, 0, stream>>>(counts, offsets, out + (size_t)NTOK * CDIM);
    k_scatter<<<NTOK / 256, 256, 0, stream>>>(tok_e, tok_w, offsets, cursor, perm_token, tok_slot);

    k_gemm1<<<NEXP * 160, 512, 0, stream>>>(xb, winb, conv_w, conv_b, Dp,
                                            counts, offsets, perm_token, y);
    k_gemm2<<<NEXP * 80, 512, 0, stream>>>(y, woutb, counts, offsets, so);
    k_combine<<<NTOK * 128 / 256, 256, 0, stream>>>(so, tok_slot, tok_w, out);
}